// Round 1
// baseline (513.789 us; speedup 1.0000x reference)
//
#include <hip/hip_runtime.h>
#include <hip/hip_bf16.h>
#include <math.h>

#define IN_DIM 64
#define HID    128
#define OUT_DIM 32
#define TILE_R 64
#define HPAD   136   // 128 + 8 shorts pad -> 272B row stride, 16B aligned
#define W1PAD  72    // 64 + 8 shorts pad  -> 144B row stride, 16B aligned

typedef short v8s __attribute__((ext_vector_type(8)));
typedef float v4f __attribute__((ext_vector_type(4)));

__device__ __forceinline__ short f2bf(float f) {
    // round-to-nearest-even fp32 -> bf16
    unsigned u = __builtin_bit_cast(unsigned, f);
    unsigned r = u + 0x7FFFu + ((u >> 16) & 1u);
    return (short)(r >> 16);
}
__device__ __forceinline__ float bf2f(short s) {
    unsigned u = ((unsigned)(unsigned short)s) << 16;
    return __builtin_bit_cast(float, u);
}
__device__ __forceinline__ float swishf(float v) {
    return v / (1.0f + __expf(-v));
}

__global__ __launch_bounds__(256, 1)
void subnet_mlp(const float* __restrict__ x,  const float* __restrict__ W1,
                const float* __restrict__ b1, const float* __restrict__ Wh,
                const float* __restrict__ bh, const float* __restrict__ Wo,
                const float* __restrict__ bo, float* __restrict__ out,
                int n_tiles)
{
    // Weights resident in LDS for the whole block lifetime (transposed: [n][k])
    __shared__ __align__(16) short sW1t[HID][W1PAD];
    __shared__ __align__(16) short sWht[2][HID][HPAD];
    __shared__ __align__(16) short sH[2][TILE_R][HPAD];   // activation ping-pong
    __shared__ float sB1[HID];
    __shared__ float sBh[2][HID];
    __shared__ float sWo[HID];
    __shared__ float sBo;

    const int tid   = threadIdx.x;
    const int o     = blockIdx.x >> 3;   // subnet
    const int slice = blockIdx.x & 7;    // row-slice of this subnet

    // ---- one-time staging: convert this subnet's weights to bf16, transposed ----
    for (int idx = tid; idx < IN_DIM * HID; idx += 256) {
        int k = idx >> 7, n = idx & 127;                 // W1[o][k][n]
        sW1t[n][k] = f2bf(W1[(o * IN_DIM + k) * HID + n]);
    }
    for (int l = 0; l < 2; ++l)
        for (int idx = tid; idx < HID * HID; idx += 256) {
            int k = idx >> 7, n = idx & 127;             // Wh[l][o][k][n]
            sWht[l][n][k] = f2bf(Wh[((l * OUT_DIM + o) * HID + k) * HID + n]);
        }
    for (int idx = tid; idx < HID; idx += 256) {
        sB1[idx]    = b1[o * HID + idx];
        sBh[0][idx] = bh[(0 * OUT_DIM + o) * HID + idx];
        sBh[1][idx] = bh[(1 * OUT_DIM + o) * HID + idx];
        sWo[idx]    = Wo[o * HID + idx];
    }
    if (tid == 0) sBo = bo[o];
    __syncthreads();

    const int lane = tid & 63;
    const int w    = tid >> 6;
    const int wr   = w >> 1;      // wave row-half (32 rows)
    const int wc   = w & 1;       // wave col-half (64 cols)
    const int m    = lane & 15;   // A/B fragment row/col index
    const int q    = lane >> 4;   // quad: k-offset q*8 in fragments

    for (int ti = slice; ti < n_tiles; ti += 8) {
        const int n0 = ti * TILE_R;

        // ================= layer 1: [64x64] @ [64x128] =================
        {
            v4f acc[2][4];
            #pragma unroll
            for (int a = 0; a < 2; ++a)
                #pragma unroll
                for (int b = 0; b < 4; ++b) acc[a][b] = (v4f)0.0f;

            #pragma unroll
            for (int kc = 0; kc < 2; ++kc) {
                v8s af[2], bfr[4];
                #pragma unroll
                for (int rt = 0; rt < 2; ++rt) {
                    const float* xp = x + (size_t)(n0 + wr * 32 + rt * 16 + m) * IN_DIM
                                        + kc * 32 + q * 8;
                    float4 x0 = *(const float4*)xp;
                    float4 x1 = *(const float4*)(xp + 4);
                    v8s a;
                    a[0] = f2bf(x0.x); a[1] = f2bf(x0.y); a[2] = f2bf(x0.z); a[3] = f2bf(x0.w);
                    a[4] = f2bf(x1.x); a[5] = f2bf(x1.y); a[6] = f2bf(x1.z); a[7] = f2bf(x1.w);
                    af[rt] = a;
                }
                #pragma unroll
                for (int ct = 0; ct < 4; ++ct)
                    bfr[ct] = *(const v8s*)&sW1t[wc * 64 + ct * 16 + m][kc * 32 + q * 8];
                #pragma unroll
                for (int rt = 0; rt < 2; ++rt)
                    #pragma unroll
                    for (int ct = 0; ct < 4; ++ct)
                        acc[rt][ct] = __builtin_amdgcn_mfma_f32_16x16x32_bf16(
                            af[rt], bfr[ct], acc[rt][ct], 0, 0, 0);
            }
            // epilogue: bias + swish -> sH[0]
            #pragma unroll
            for (int rt = 0; rt < 2; ++rt)
                #pragma unroll
                for (int ct = 0; ct < 4; ++ct)
                    #pragma unroll
                    for (int r = 0; r < 4; ++r) {
                        int row = wr * 32 + rt * 16 + q * 4 + r;
                        int col = wc * 64 + ct * 16 + m;
                        float v = acc[rt][ct][r] + sB1[col];
                        sH[0][row][col] = f2bf(swishf(v));
                    }
        }
        __syncthreads();

        // ================= hidden layers: [64x128] @ [128x128] =================
        #pragma unroll
        for (int l = 0; l < 2; ++l) {
            const int cin = l, cout = 1 - l;
            v4f acc[2][4];
            #pragma unroll
            for (int a = 0; a < 2; ++a)
                #pragma unroll
                for (int b = 0; b < 4; ++b) acc[a][b] = (v4f)0.0f;

            #pragma unroll
            for (int kc = 0; kc < 4; ++kc) {
                v8s af[2], bfr[4];
                #pragma unroll
                for (int rt = 0; rt < 2; ++rt)
                    af[rt] = *(const v8s*)&sH[cin][wr * 32 + rt * 16 + m][kc * 32 + q * 8];
                #pragma unroll
                for (int ct = 0; ct < 4; ++ct)
                    bfr[ct] = *(const v8s*)&sWht[l][wc * 64 + ct * 16 + m][kc * 32 + q * 8];
                #pragma unroll
                for (int rt = 0; rt < 2; ++rt)
                    #pragma unroll
                    for (int ct = 0; ct < 4; ++ct)
                        acc[rt][ct] = __builtin_amdgcn_mfma_f32_16x16x32_bf16(
                            af[rt], bfr[ct], acc[rt][ct], 0, 0, 0);
            }
            #pragma unroll
            for (int rt = 0; rt < 2; ++rt)
                #pragma unroll
                for (int ct = 0; ct < 4; ++ct)
                    #pragma unroll
                    for (int r = 0; r < 4; ++r) {
                        int row = wr * 32 + rt * 16 + q * 4 + r;
                        int col = wc * 64 + ct * 16 + m;
                        float v = acc[rt][ct][r] + sBh[l][col];
                        sH[cout][row][col] = f2bf(swishf(v));
                    }
            __syncthreads();
        }

        // ================= head: [64x128] . Wo[128] -> out[64] =================
        {
            const int r = tid >> 2, qd = tid & 3;
            float sum = 0.0f;
            #pragma unroll
            for (int j = 0; j < 32; ++j)
                sum += bf2f(sH[0][r][qd * 32 + j]) * sWo[qd * 32 + j];
            sum += __shfl_xor(sum, 1);
            sum += __shfl_xor(sum, 2);
            if (qd == 0)
                out[(size_t)(n0 + r) * OUT_DIM + o] = sum + sBo;
        }
        __syncthreads();   // protect sH[0] before next iteration's layer-1 writes
    }
}

extern "C" void kernel_launch(void* const* d_in, const int* in_sizes, int n_in,
                              void* d_out, int out_size, void* d_ws, size_t ws_size,
                              hipStream_t stream) {
    const float* x  = (const float*)d_in[0];
    const float* W1 = (const float*)d_in[1];
    const float* b1 = (const float*)d_in[2];
    const float* Wh = (const float*)d_in[3];
    const float* bh = (const float*)d_in[4];
    const float* Wo = (const float*)d_in[5];
    const float* bo = (const float*)d_in[6];
    float* out = (float*)d_out;

    const int N = in_sizes[0] / IN_DIM;      // 32768
    const int n_tiles = N / TILE_R;          // 512

    dim3 grid(OUT_DIM * 8);                  // 256 blocks = 1 per CU (LDS-limited)
    dim3 block(256);
    subnet_mlp<<<grid, block, 0, stream>>>(x, W1, b1, Wh, bh, Wo, bo, out, n_tiles);
}

// Round 2
// 315.454 us; speedup vs baseline: 1.6287x; 1.6287x over previous
//
#include <hip/hip_runtime.h>
#include <hip/hip_bf16.h>

#define IN_DIM  64
#define HID     128
#define OUT_DIM 32
#define W1P     72    // 64 k + pad  (144 B row, 16B-aligned, stride 36 banks -> 2-way max)
#define WHP     136   // 128 k + pad (272 B row, 16B-aligned, stride 68 banks -> 2-way max)
#define HP      136

typedef short v8s __attribute__((ext_vector_type(8)));
typedef float v4f __attribute__((ext_vector_type(4)));

__device__ __forceinline__ short f2bf(float f) {
    // round-to-nearest-even fp32 -> bf16 (staging only)
    unsigned u = __builtin_bit_cast(unsigned, f);
    unsigned r = u + 0x7FFFu + ((u >> 16) & 1u);
    return (short)(r >> 16);
}
__device__ __forceinline__ float swishf(float v) {
    // v * sigmoid(v) with native v_exp / v_rcp
    return __fdividef(v, 1.0f + __expf(-v));
}

// Transposed-GEMM structure: every layer computes C^T = W^T * H^T.
//   A-frag  = W^T from LDS (k-contiguous v8s)
//   B-frag  = H row-major  (k-contiguous v8s)  -- no transpose ever needed
//   C^T out = lane holds 4 consecutive OUTPUT CHANNELS of one row -> packed b64 write
// Each wave owns a private 16-row slab of H -> zero __syncthreads in main loop.
__global__ __launch_bounds__(512, 2)
void subnet_mlp(const float* __restrict__ x,  const float* __restrict__ W1,
                const float* __restrict__ b1, const float* __restrict__ Wh,
                const float* __restrict__ bh, const float* __restrict__ Wo,
                const float* __restrict__ bo, float* __restrict__ out,
                int n_iters)
{
    __shared__ __align__(16) short sW1t[HID][W1P];      // W1^T[c][k]
    __shared__ __align__(16) short sWht[2][HID][WHP];   // Wh^T[l][c][k]
    __shared__ __align__(16) short sH[8][16][HP];       // per-wave row-major slabs
    __shared__ __align__(16) float sB1[HID];
    __shared__ __align__(16) float sBh[2][HID];
    __shared__ __align__(16) float sWo[HID];

    const int tid   = threadIdx.x;
    const int o     = blockIdx.x >> 4;    // subnet
    const int slice = blockIdx.x & 15;    // row-slice

    // ---- one-time staging: this subnet's weights, bf16, transposed ----
    for (int idx = tid; idx < IN_DIM * HID; idx += 512) {
        int c = idx & 127, k = idx >> 7;            // consecutive tid -> consecutive c (coalesced)
        sW1t[c][k] = f2bf(W1[(o * IN_DIM + k) * HID + c]);
    }
    #pragma unroll
    for (int l = 0; l < 2; ++l)
        for (int idx = tid; idx < HID * HID; idx += 512) {
            int c = idx & 127, k = idx >> 7;
            sWht[l][c][k] = f2bf(Wh[((l * OUT_DIM + o) * HID + k) * HID + c]);
        }
    if (tid < HID) {
        sB1[tid]    = b1[o * HID + tid];
        sBh[0][tid] = bh[o * HID + tid];
        sBh[1][tid] = bh[(OUT_DIM + o) * HID + tid];
        sWo[tid]    = Wo[o * HID + tid];
    }
    __syncthreads();   // the ONLY block-wide barrier

    const int lane = tid & 63;
    const int w    = tid >> 6;    // wave id: owns rows [w*16, w*16+16) of each tile
    const int n    = lane & 15;   // fragment row/col index
    const int q    = lane >> 4;   // quad
    const float bo_v = bo[o];

    // head weights for this lane's 32 output channels (c = 16*ct + 4*q + reg)
    v4f wo4[8];
    #pragma unroll
    for (int ct = 0; ct < 8; ++ct)
        wo4[ct] = *(const v4f*)&sWo[ct * 16 + 4 * q];

    for (int it = 0; it < n_iters; ++it) {
        const int n0  = (slice * n_iters + it) * 128;
        const int row = n0 + w * 16 + n;

        // ================= layer 1: C1^T = W1^T @ X^T =================
        v8s xb[2];
        #pragma unroll
        for (int kc = 0; kc < 2; ++kc) {
            const float* xp = x + row * IN_DIM + kc * 32 + q * 8;
            float4 f0 = *(const float4*)xp;
            float4 f1 = *(const float4*)(xp + 4);
            union { v8s v; unsigned u[4]; } cv;
            __hip_bfloat162 p;
            p = __float22bfloat162_rn(make_float2(f0.x, f0.y)); cv.u[0] = *(unsigned*)&p;
            p = __float22bfloat162_rn(make_float2(f0.z, f0.w)); cv.u[1] = *(unsigned*)&p;
            p = __float22bfloat162_rn(make_float2(f1.x, f1.y)); cv.u[2] = *(unsigned*)&p;
            p = __float22bfloat162_rn(make_float2(f1.z, f1.w)); cv.u[3] = *(unsigned*)&p;
            xb[kc] = cv.v;
        }
        v4f acc[8];
        #pragma unroll
        for (int ct = 0; ct < 8; ++ct)           // bias rides the accumulator init
            acc[ct] = *(const v4f*)&sB1[ct * 16 + 4 * q];
        #pragma unroll
        for (int kc = 0; kc < 2; ++kc)
            #pragma unroll
            for (int ct = 0; ct < 8; ++ct) {
                v8s a = *(const v8s*)&sW1t[ct * 16 + n][kc * 32 + q * 8];
                acc[ct] = __builtin_amdgcn_mfma_f32_16x16x32_bf16(a, xb[kc], acc[ct], 0, 0, 0);
            }
        #pragma unroll
        for (int ct = 0; ct < 8; ++ct) {         // swish + packed b64 store, row-major H
            float s0 = swishf(acc[ct][0]);
            float s1 = swishf(acc[ct][1]);
            float s2 = swishf(acc[ct][2]);
            float s3 = swishf(acc[ct][3]);
            __hip_bfloat162 p0 = __float22bfloat162_rn(make_float2(s0, s1));
            __hip_bfloat162 p1 = __float22bfloat162_rn(make_float2(s2, s3));
            uint2 pk; pk.x = *(unsigned*)&p0; pk.y = *(unsigned*)&p1;
            *(uint2*)&sH[w][n][ct * 16 + 4 * q] = pk;
        }

        // ================= hidden layers: C^T = Wh^T @ H^T =================
        #pragma unroll
        for (int l = 0; l < 2; ++l) {
            v8s hb[4];
            #pragma unroll
            for (int kc = 0; kc < 4; ++kc)       // load ALL B-frags before overwriting slab
                hb[kc] = *(const v8s*)&sH[w][n][kc * 32 + q * 8];
            #pragma unroll
            for (int ct = 0; ct < 8; ++ct)
                acc[ct] = *(const v4f*)&sBh[l][ct * 16 + 4 * q];
            #pragma unroll
            for (int kc = 0; kc < 4; ++kc)
                #pragma unroll
                for (int ct = 0; ct < 8; ++ct) {
                    v8s a = *(const v8s*)&sWht[l][ct * 16 + n][kc * 32 + q * 8];
                    acc[ct] = __builtin_amdgcn_mfma_f32_16x16x32_bf16(a, hb[kc], acc[ct], 0, 0, 0);
                }
            if (l == 0) {
                #pragma unroll
                for (int ct = 0; ct < 8; ++ct) {
                    float s0 = swishf(acc[ct][0]);
                    float s1 = swishf(acc[ct][1]);
                    float s2 = swishf(acc[ct][2]);
                    float s3 = swishf(acc[ct][3]);
                    __hip_bfloat162 p0 = __float22bfloat162_rn(make_float2(s0, s1));
                    __hip_bfloat162 p1 = __float22bfloat162_rn(make_float2(s2, s3));
                    uint2 pk; pk.x = *(unsigned*)&p0; pk.y = *(unsigned*)&p1;
                    *(uint2*)&sH[w][n][ct * 16 + 4 * q] = pk;
                }
            } else {
                // head fused into the epilogue: no third LDS round trip
                float partial = 0.0f;
                #pragma unroll
                for (int ct = 0; ct < 8; ++ct) {
                    partial += swishf(acc[ct][0]) * wo4[ct][0];
                    partial += swishf(acc[ct][1]) * wo4[ct][1];
                    partial += swishf(acc[ct][2]) * wo4[ct][2];
                    partial += swishf(acc[ct][3]) * wo4[ct][3];
                }
                partial += __shfl_xor(partial, 16);   // reduce across the 4 quads
                partial += __shfl_xor(partial, 32);
                if (lane < 16)
                    out[row * OUT_DIM + o] = partial + bo_v;
            }
        }
    }
}

extern "C" void kernel_launch(void* const* d_in, const int* in_sizes, int n_in,
                              void* d_out, int out_size, void* d_ws, size_t ws_size,
                              hipStream_t stream) {
    const float* x  = (const float*)d_in[0];
    const float* W1 = (const float*)d_in[1];
    const float* b1 = (const float*)d_in[2];
    const float* Wh = (const float*)d_in[3];
    const float* bh = (const float*)d_in[4];
    const float* Wo = (const float*)d_in[5];
    const float* bo = (const float*)d_in[6];
    float* out = (float*)d_out;

    const int N       = in_sizes[0] / IN_DIM;  // 32768
    const int n_tiles = N / 128;               // 256 tiles of 128 rows
    const int n_iters = n_tiles / 16;          // 16 tiles per block

    dim3 grid(OUT_DIM * 16);                   // 512 blocks: 32 subnets x 16 slices
    dim3 block(512);                           // 8 waves = 2/SIMD
    subnet_mlp<<<grid, block, 0, stream>>>(x, W1, b1, Wh, bh, Wo, bo, out, n_iters);
}